// Round 11
// baseline (74.599 us; speedup 1.0000x reference)
//
#include <hip/hip_runtime.h>
#include <hip/hip_bf16.h>
#include <math.h>

typedef _Float16 f16_t;
typedef _Float16 f16x8 __attribute__((ext_vector_type(8)));
typedef float f32x16 __attribute__((ext_vector_type(16)));
typedef unsigned int uintx4 __attribute__((ext_vector_type(4)));
typedef unsigned int uintx2 __attribute__((ext_vector_type(2)));

#define NROWS 32768
#define DD 32
#define SIG_OFF (NROWS * 64)

// ---------------- ws layout (f16 elements) ----------------
// GEMM weights in PER-WAVE FRAGMENT-LOAD ORDER: [tile][ks][lane][j(0..7)],
// lane = l31 + 32*lh; n = tile*32 + l31; k = ks*16 + lh*8 + j.
// Per-d superblock: wf2(4096) | wf3(8192) = 12288 f16 = 24KB.
#define PERD_STRIDE 12288
#define W1B1F_OFF  393216          // [32 d][128] : w1[0..63] | b1[64..127]
#define RW1F_OFF   397312          // 2t x 8ks x 512 (rW1[k][n], k<128)
#define RW2F_OFF   405504          // 2t x 4ks x 512 (rW2[k][n], k<64)
#define RW3F_OFF   409600          // 4nt x 4ks x 512 (rW3[k][n], n<128)
#define B3F_OFF    417792          // 4t x 2ks x 512 (b3[d][n] as B-frag, "k"=d)
#define WS_ELEMS   421888

__global__ void convert_weights(const float* __restrict__ W1,
                                const float* __restrict__ b1,
                                const float* __restrict__ W2,
                                const float* __restrict__ W3,
                                const float* __restrict__ b3,
                                const float* __restrict__ rW1,
                                const float* __restrict__ rW2,
                                const float* __restrict__ rW3,
                                f16_t* __restrict__ ws) {
  for (int i = blockIdx.x * blockDim.x + threadIdx.x; i < WS_ELEMS;
       i += gridDim.x * blockDim.x) {
    float v;
    if (i < W1B1F_OFF) {
      int d = i / PERD_STRIDE;
      int r = i - d * PERD_STRIDE;
      if (r < 4096) {                 // wf2 fragments: W2[d][k][n], n<64
        int t = r >> 11, ks = (r >> 9) & 3, lane = (r >> 3) & 63, j = r & 7;
        int n = t * 32 + (lane & 31);
        int k = ks * 16 + (lane >> 5) * 8 + j;
        v = W2[(d * 64 + k) * 64 + n];
      } else {                        // wf3 fragments: W3[d][k][n], n<128
        int r2 = r - 4096;
        int t = r2 >> 11, ks = (r2 >> 9) & 3, lane = (r2 >> 3) & 63, j = r2 & 7;
        int n = t * 32 + (lane & 31);
        int k = ks * 16 + (lane >> 5) * 8 + j;
        v = W3[(d * 64 + k) * 128 + n];
      }
    } else if (i < RW1F_OFF) {        // w1 | b1, [d][128]
      int jj = i - W1B1F_OFF;
      int d = jj >> 7, c = jj & 127;
      v = (c < 64) ? W1[d * 64 + c] : b1[d * 64 + (c - 64)];
    } else if (i < RW2F_OFF) {        // rW1 fragments, k<128
      int i2 = i - RW1F_OFF;
      int t = i2 >> 12, ks = (i2 >> 9) & 7, lane = (i2 >> 3) & 63, j = i2 & 7;
      int n = t * 32 + (lane & 31);
      int k = ks * 16 + (lane >> 5) * 8 + j;
      v = rW1[k * 64 + n];
    } else if (i < RW3F_OFF) {        // rW2 fragments, k<64
      int i2 = i - RW2F_OFF;
      int t = i2 >> 11, ks = (i2 >> 9) & 3, lane = (i2 >> 3) & 63, j = i2 & 7;
      int n = t * 32 + (lane & 31);
      int k = ks * 16 + (lane >> 5) * 8 + j;
      v = rW2[k * 64 + n];
    } else if (i < B3F_OFF) {         // rW3 fragments, output col n<128, k<64
      int i2 = i - RW3F_OFF;
      int nt = i2 >> 11, ks = (i2 >> 9) & 3, lane = (i2 >> 3) & 63, j = i2 & 7;
      int n = nt * 32 + (lane & 31);
      int k = ks * 16 + (lane >> 5) * 8 + j;
      v = rW3[k * 128 + n];
    } else {                          // b3 as B-fragment: "k" axis = d (32)
      int i2 = i - B3F_OFF;
      int t = i2 >> 10, ks = (i2 >> 9) & 1, lane = (i2 >> 3) & 63, j = i2 & 7;
      int n = t * 32 + (lane & 31);
      int dsrc = ks * 16 + (lane >> 5) * 8 + j;
      v = b3[dsrc * 128 + n];
    }
    ws[i] = (f16_t)v;
  }
}

// Swapped-C tile (lane = data-row l31, regs: n=(reg&3)+8*(reg>>2)+4*lh) ->
// two B fragments via a PER-WAVE private LDS round-trip (no barrier; the
// within-wave ds_write->ds_read dependence is compiler-ordered).
__device__ __forceinline__ void xpose2(const f32x16& c, unsigned* row, int lh,
                                       f16x8& o0, f16x8& o1) {
  #pragma unroll
  for (int a = 0; a < 4; ++a) {
    uintx2 w;
    w.x = __builtin_bit_cast(unsigned, __builtin_amdgcn_cvt_pkrtz(c[4 * a + 0], c[4 * a + 1]));
    w.y = __builtin_bit_cast(unsigned, __builtin_amdgcn_cvt_pkrtz(c[4 * a + 2], c[4 * a + 3]));
    *reinterpret_cast<uintx2*>(row + 4 * a + 2 * lh) = w;
  }
  uintx2 ra = *reinterpret_cast<const uintx2*>(row + 4 * lh);
  uintx2 rb = *reinterpret_cast<const uintx2*>(row + 4 * lh + 2);
  uintx2 rc = *reinterpret_cast<const uintx2*>(row + 8 + 4 * lh);
  uintx2 rd = *reinterpret_cast<const uintx2*>(row + 8 + 4 * lh + 2);
  uintx4 w0 = {ra.x, ra.y, rb.x, rb.y};
  uintx4 w1 = {rc.x, rc.y, rd.x, rd.y};
  o0 = __builtin_bit_cast(f16x8, w0);
  o1 = __builtin_bit_cast(f16x8, w1);
}

// GEMM1 for one 32-row subtile: h1 -> h2^T = W2T x h1^T (+b2, relu, mask) ->
// xpose -> B fragments pf[4]. wf2 is passed in (register-shared across the
// two subtiles of a 64-row wave -- the whole point: one LDS fragment read
// serves 64 rows).
__device__ __forceinline__ void gemm1_32(const f16x8 wf2[2][4],
                                         const f16_t* __restrict__ w1b1row,
                                         const float* __restrict__ b2row,
                                         unsigned* xr0, unsigned* xr1,
                                         float xv, bool mb, int lh,
                                         f16x8* pf) {
  f16_t xh = (f16_t)xv;
  f16x8 xv8 = {xh, xh, xh, xh, xh, xh, xh, xh};
  f16x8 h1f[4];
  #pragma unroll
  for (int ks = 0; ks < 4; ++ks) {
    f16x8 w1 = *reinterpret_cast<const f16x8*>(w1b1row + ks * 16 + lh * 8);
    f16x8 bb = *reinterpret_cast<const f16x8*>(w1b1row + 64 + ks * 16 + lh * 8);
    f16x8 h = xv8 * w1 + bb;
    h1f[ks] = __builtin_elementwise_max(h, (f16x8)(f16_t)0);
  }
  f32x16 hacc[2];
  #pragma unroll
  for (int t = 0; t < 2; ++t)
    #pragma unroll
    for (int a = 0; a < 4; ++a) {
      float4 bv = *reinterpret_cast<const float4*>(b2row + t * 32 + a * 8 + lh * 4);
      hacc[t][4 * a + 0] = bv.x; hacc[t][4 * a + 1] = bv.y;
      hacc[t][4 * a + 2] = bv.z; hacc[t][4 * a + 3] = bv.w;
    }
  #pragma unroll
  for (int ks = 0; ks < 4; ++ks) {
    hacc[0] = __builtin_amdgcn_mfma_f32_32x32x16_f16(wf2[0][ks], h1f[ks], hacc[0], 0, 0, 0);
    hacc[1] = __builtin_amdgcn_mfma_f32_32x32x16_f16(wf2[1][ks], h1f[ks], hacc[1], 0, 0, 0);
  }
  #pragma unroll
  for (int t = 0; t < 2; ++t)
    #pragma unroll
    for (int r = 0; r < 16; ++r) {
      float v = fmaxf(hacc[t][r], 0.f);
      hacc[t][r] = mb ? v : 0.f;
    }
  xpose2(hacc[0], xr0, lh, pf[0], pf[1]);
  xpose2(hacc[1], xr1, lh, pf[2], pf[3]);
}

// Readout chain for one 32-row subtile (pooled acc -> mu | softplus(sigma)).
__device__ __forceinline__ void readout32(f32x16* acc, unsigned mword,
                                          const f16_t* __restrict__ ws,
                                          const float* __restrict__ rb,
                                          unsigned* xr0, unsigned* xr1,
                                          int lane16, int l31, int lh,
                                          int rowb, float* __restrict__ out) {
  // ---- pooled += maskT @ b3 (bias of masked sum), 8 MFMA ----
  {
    f16x8 mf[2];
    #pragma unroll
    for (int ks = 0; ks < 2; ++ks) {
      unsigned w[4];
      #pragma unroll
      for (int ii = 0; ii < 4; ++ii) {
        int d0 = ks * 16 + lh * 8 + 2 * ii;
        w[ii] = (((mword >> d0) & 1u) ? 0x3C00u : 0u) |
                (((mword >> (d0 + 1)) & 1u) ? 0x3C000000u : 0u);
      }
      uintx4 ww = {w[0], w[1], w[2], w[3]};
      mf[ks] = __builtin_bit_cast(f16x8, ww);
    }
    const f16_t* b3f = ws + B3F_OFF;
    #pragma unroll
    for (int t = 0; t < 4; ++t)
      #pragma unroll
      for (int ks = 0; ks < 2; ++ks) {
        f16x8 bf = *reinterpret_cast<const f16x8*>(b3f + (t * 2 + ks) * 512 + lane16);
        acc[t] = __builtin_amdgcn_mfma_f32_32x32x16_f16(bf, mf[ks], acc[t], 0, 0, 0);
      }
  }
  // ---- R1 (swapped): r1^T = rW1T x pooled^T, K=128 ----
  f16x8 poolf[8];
  xpose2(acc[0], xr0, lh, poolf[0], poolf[1]);
  xpose2(acc[1], xr1, lh, poolf[2], poolf[3]);
  xpose2(acc[2], xr0, lh, poolf[4], poolf[5]);
  xpose2(acc[3], xr1, lh, poolf[6], poolf[7]);
  f32x16 r1[2];
  #pragma unroll
  for (int t = 0; t < 2; ++t)
    #pragma unroll
    for (int a = 0; a < 4; ++a) {
      float4 bv = *reinterpret_cast<const float4*>(&rb[t * 32 + a * 8 + lh * 4]);
      r1[t][4 * a + 0] = bv.x; r1[t][4 * a + 1] = bv.y;
      r1[t][4 * a + 2] = bv.z; r1[t][4 * a + 3] = bv.w;
    }
  {
    const f16_t* rw1 = ws + RW1F_OFF;
    #pragma unroll
    for (int t = 0; t < 2; ++t)
      #pragma unroll
      for (int ks = 0; ks < 8; ++ks) {
        f16x8 wf = *reinterpret_cast<const f16x8*>(rw1 + (t * 8 + ks) * 512 + lane16);
        r1[t] = __builtin_amdgcn_mfma_f32_32x32x16_f16(wf, poolf[ks], r1[t], 0, 0, 0);
      }
  }
  #pragma unroll
  for (int t = 0; t < 2; ++t)
    #pragma unroll
    for (int r = 0; r < 16; ++r) r1[t][r] = fmaxf(r1[t][r], 0.f);

  // ---- R2 (swapped): r2^T = rW2T x r1^T, K=64 ----
  f16x8 r1f[4];
  xpose2(r1[0], xr0, lh, r1f[0], r1f[1]);
  xpose2(r1[1], xr1, lh, r1f[2], r1f[3]);
  f32x16 r2[2];
  #pragma unroll
  for (int t = 0; t < 2; ++t)
    #pragma unroll
    for (int a = 0; a < 4; ++a) {
      float4 bv = *reinterpret_cast<const float4*>(&rb[64 + t * 32 + a * 8 + lh * 4]);
      r2[t][4 * a + 0] = bv.x; r2[t][4 * a + 1] = bv.y;
      r2[t][4 * a + 2] = bv.z; r2[t][4 * a + 3] = bv.w;
    }
  {
    const f16_t* rw2 = ws + RW2F_OFF;
    #pragma unroll
    for (int t = 0; t < 2; ++t)
      #pragma unroll
      for (int ks = 0; ks < 4; ++ks) {
        f16x8 wf = *reinterpret_cast<const f16x8*>(rw2 + (t * 4 + ks) * 512 + lane16);
        r2[t] = __builtin_amdgcn_mfma_f32_32x32x16_f16(wf, r1f[ks], r2[t], 0, 0, 0);
      }
  }
  #pragma unroll
  for (int t = 0; t < 2; ++t)
    #pragma unroll
    for (int r = 0; r < 16; ++r) r2[t][r] = fmaxf(r2[t][r], 0.f);

  // ---- R3 (NON-swapped for coalesced stores): o = r2 @ rW3, N=128 ----
  f16x8 r2f[4];
  xpose2(r2[0], xr0, lh, r2f[0], r2f[1]);
  xpose2(r2[1], xr1, lh, r2f[2], r2f[3]);
  f32x16 oacc[4] = {};
  {
    const f16_t* rw3 = ws + RW3F_OFF;
    #pragma unroll
    for (int nt = 0; nt < 4; ++nt)
      #pragma unroll
      for (int ks = 0; ks < 4; ++ks) {
        f16x8 wf = *reinterpret_cast<const f16x8*>(rw3 + (nt * 4 + ks) * 512 + lane16);
        oacc[nt] = __builtin_amdgcn_mfma_f32_32x32x16_f16(r2f[ks], wf, oacc[nt], 0, 0, 0);
      }
  }
  #pragma unroll
  for (int nt = 0; nt < 4; ++nt) {
    float rbv = rb[128 + nt * 32 + l31];
    #pragma unroll
    for (int r = 0; r < 16; ++r) {
      int rl = (r & 3) + 8 * (r >> 2) + 4 * lh;
      size_t grow = (size_t)(rowb + rl);
      float v = oacc[nt][r] + rbv;
      if (nt < 2) {
        out[grow * 64 + nt * 32 + l31] = v;
      } else {
        float sp = fmaxf(v, 0.f) + __logf(1.f + __expf(-fabsf(v)));
        out[(size_t)SIG_OFF + grow * 64 + (nt - 2) * 32 + l31] = sp;
      }
    }
  }
}

// Round 11 structure: block = 512 thr = 8 waves. Wave (pr = wid>>2, q = wid&3):
// pr owns 64 rows (2 subtiles) blk*128 + pr*64 + {l31, 32+l31}; q owns the
// d-quarter [8q, 8q+8). FOUR single-buffered 24KB LDS weight streams (96KB);
// per iter: {compute both subtiles from wbuf[q] -- ONE wf2/wf3 LDS fragment
// read feeds TWO MFMAs (64 rows); issue 12 global loads; barrier; ds_write;
// barrier}. This halves the dominant LDS term (r10 post-mortem: r9 vs r10
// moved identical ~5.8MB LDS/CU and both sat at ~55us -> LDS-port-bound;
// fragment reads were 3MB of it). Pool: 4-way q-combine through dead wbuf.
__launch_bounds__(512, 2)
__global__ void indexnet_main(const float* __restrict__ x,
                              const int* __restrict__ mask,
                              const float* __restrict__ b2,
                              const float* __restrict__ rb1,
                              const float* __restrict__ rb2,
                              const float* __restrict__ rb3,
                              const f16_t* __restrict__ ws,
                              float* __restrict__ out) {
  __shared__ __align__(16) f16_t wbuf[4][12288];       // 96KB: 4 q-streams
  __shared__ __align__(16) f16_t w1b1_lds[32][128];    // 8KB
  __shared__ float b2_lds[32][64];                     // 8KB
  __shared__ float rb_lds[256];                        // 1KB
  __shared__ __align__(16) unsigned xp_lds[8][2][32][18];  // 36.9KB
  // total 150.6KB -> 1 block/CU, 8 waves/CU = 2 waves/SIMD

  const int tid = threadIdx.x;
  const int lane = tid & 63;
  const int wid = tid >> 6;
  const int pr = wid >> 2;         // row group (0..1), 64 rows each
  const int q = wid & 3;           // d-quarter
  const int l31 = lane & 31;
  const int lh = lane >> 5;
  const int row0 = blockIdx.x * 128;
  const int lane16 = lane * 8;

  unsigned* xr0 = &xp_lds[wid][0][l31][0];
  unsigned* xr1 = &xp_lds[wid][1][l31][0];

  // ---- stage b2 [32][64] f32 (512 x float4) ----
  {
    float4* dst = reinterpret_cast<float4*>(&b2_lds[0][0]);
    const float4* src = reinterpret_cast<const float4*>(b2);
    dst[tid] = src[tid];
  }
  // ---- stage readout biases ----
  if (tid < 64)        rb_lds[tid] = rb1[tid];
  else if (tid < 128)  rb_lds[tid] = rb2[tid - 64];
  else if (tid < 256)  rb_lds[tid] = rb3[tid - 128];
  // ---- stage w1|b1 [32][128] f16 (512 x 16B) ----
  {
    const uintx4* src = reinterpret_cast<const uintx4*>(ws + W1B1F_OFF);
    uintx4* dst = reinterpret_cast<uintx4*>(&w1b1_lds[0][0]);
    dst[tid] = src[tid];
  }
  // ---- per-lane mask words for BOTH own rows ----
  unsigned mwordA = 0, mwordB = 0;
  {
    const int4* mrA = reinterpret_cast<const int4*>(mask + (size_t)(row0 + pr * 64 + l31) * DD);
    const int4* mrB = reinterpret_cast<const int4*>(mask + (size_t)(row0 + pr * 64 + 32 + l31) * DD);
    #pragma unroll
    for (int c4 = 0; c4 < 8; ++c4) {
      int4 a = mrA[c4];
      int4 b = mrB[c4];
      mwordA |= (a.x != 0 ? 1u : 0u) << (4 * c4);
      mwordA |= (a.y != 0 ? 1u : 0u) << (4 * c4 + 1);
      mwordA |= (a.z != 0 ? 1u : 0u) << (4 * c4 + 2);
      mwordA |= (a.w != 0 ? 1u : 0u) << (4 * c4 + 3);
      mwordB |= (b.x != 0 ? 1u : 0u) << (4 * c4);
      mwordB |= (b.y != 0 ? 1u : 0u) << (4 * c4 + 1);
      mwordB |= (b.z != 0 ? 1u : 0u) << (4 * c4 + 2);
      mwordB |= (b.w != 0 ? 1u : 0u) << (4 * c4 + 3);
    }
  }
  const int qbase = q * 8;
  const float* xrowA = x + (size_t)(row0 + pr * 64 + l31) * DD + qbase;
  const float* xrowB = x + (size_t)(row0 + pr * 64 + 32 + l31) * DD + qbase;

  // ---- prologue: stage d = {0,8,16,24} into the 4 streams ----
  #pragma unroll
  for (int s = 0; s < 4; ++s)
    #pragma unroll
    for (int c = 0; c < 3; ++c) {
      f16x8 v = *reinterpret_cast<const f16x8*>(
          ws + (size_t)(s * 8) * PERD_STRIDE + c * 4096 + tid * 8);
      *reinterpret_cast<f16x8*>(&wbuf[s][c * 4096 + tid * 8]) = v;
    }
  __syncthreads();

  f32x16 accA[4] = {}, accB[4] = {};
  float4 xa4, xb4;

  #pragma unroll
  for (int i = 0; i < 8; ++i) {
    if ((i & 3) == 0) {
      xa4 = *reinterpret_cast<const float4*>(xrowA + i);
      xb4 = *reinterpret_cast<const float4*>(xrowB + i);
    }
    const int d = qbase + i;
    float xvA = ((i & 3) == 0) ? xa4.x : ((i & 3) == 1) ? xa4.y
              : ((i & 3) == 2) ? xa4.z : xa4.w;
    float xvB = ((i & 3) == 0) ? xb4.x : ((i & 3) == 1) ? xb4.y
              : ((i & 3) == 2) ? xb4.z : xb4.w;

    // ---- compute both subtiles from this wave's stream ----
    const f16_t* wb = &wbuf[q][0];
    f16x8 wf2[2][4];
    #pragma unroll
    for (int t = 0; t < 2; ++t)
      #pragma unroll
      for (int ks = 0; ks < 4; ++ks)
        wf2[t][ks] = *reinterpret_cast<const f16x8*>(wb + (t * 4 + ks) * 512 + lane16);
    f16x8 pfA[4], pfB[4];
    gemm1_32(wf2, &w1b1_lds[d][0], &b2_lds[d][0], xr0, xr1,
             xvA, (mwordA >> d) & 1u, lh, pfA);
    gemm1_32(wf2, &w1b1_lds[d][0], &b2_lds[d][0], xr0, xr1,
             xvB, (mwordB >> d) & 1u, lh, pfB);
    #pragma unroll
    for (int t = 0; t < 4; ++t) {
      f16x8 w3[4];
      #pragma unroll
      for (int ks = 0; ks < 4; ++ks)
        w3[ks] = *reinterpret_cast<const f16x8*>(wb + 4096 + (t * 4 + ks) * 512 + lane16);
      #pragma unroll
      for (int ks = 0; ks < 4; ++ks) {
        accA[t] = __builtin_amdgcn_mfma_f32_32x32x16_f16(w3[ks], pfA[ks], accA[t], 0, 0, 0);
        accB[t] = __builtin_amdgcn_mfma_f32_32x32x16_f16(w3[ks], pfB[ks], accB[t], 0, 0, 0);
      }
    }

    // ---- refill all 4 streams with next d (single-buffered: 2 barriers) ----
    if (i < 7) {
      f16x8 st[12];
      #pragma unroll
      for (int s = 0; s < 4; ++s)
        #pragma unroll
        for (int c = 0; c < 3; ++c)
          st[s * 3 + c] = *reinterpret_cast<const f16x8*>(
              ws + (size_t)(s * 8 + i + 1) * PERD_STRIDE + c * 4096 + tid * 8);
      __syncthreads();   // all waves done reading current superblocks
      #pragma unroll
      for (int s = 0; s < 4; ++s)
        #pragma unroll
        for (int c = 0; c < 3; ++c)
          *reinterpret_cast<f16x8*>(&wbuf[s][c * 4096 + tid * 8]) = st[s * 3 + c];
      __syncthreads();   // new superblocks visible
    }
  }
  __syncthreads();   // last compute done before pool aliases wbuf

  // ---- pool combine across the 4 q-quarters (aliased onto dead wbuf) ----
  // layout: float4[ci][a][lane], ci = ((pr*2+sub)*4+t)*2+lh -- contiguous
  // 16B/lane rows, conflict-free.
  float4* pool4 = reinterpret_cast<float4*>(&wbuf[0][0]);
  #pragma unroll 1
  for (int qq = 1; qq <= 3; ++qq) {
    if (q == qq) {
      #pragma unroll
      for (int sub = 0; sub < 2; ++sub) {
        f32x16* acc = sub ? accB : accA;
        #pragma unroll
        for (int t = 0; t < 4; ++t) {
          int ci = ((pr * 2 + sub) * 4 + t) * 2 + lh;
          #pragma unroll
          for (int a = 0; a < 4; ++a) {
            float4 f = {acc[t][4 * a], acc[t][4 * a + 1],
                        acc[t][4 * a + 2], acc[t][4 * a + 3]};
            pool4[(ci * 4 + a) * 32 + l31] = f;
          }
        }
      }
    }
    __syncthreads();
    if (q == 0) {
      #pragma unroll
      for (int sub = 0; sub < 2; ++sub) {
        f32x16* acc = sub ? accB : accA;
        #pragma unroll
        for (int t = 0; t < 4; ++t) {
          int ci = ((pr * 2 + sub) * 4 + t) * 2 + lh;
          #pragma unroll
          for (int a = 0; a < 4; ++a) {
            float4 f = pool4[(ci * 4 + a) * 32 + l31];
            acc[t][4 * a + 0] += f.x; acc[t][4 * a + 1] += f.y;
            acc[t][4 * a + 2] += f.z; acc[t][4 * a + 3] += f.w;
          }
        }
      }
    }
    __syncthreads();
  }
  if (q != 0) return;

  // ---- readout: q0 waves handle both subtiles of their 64 rows ----
  readout32(accA, mwordA, ws, rb_lds, xr0, xr1, lane16, l31, lh,
            row0 + pr * 64, out);
  readout32(accB, mwordB, ws, rb_lds, xr0, xr1, lane16, l31, lh,
            row0 + pr * 64 + 32, out);
}

extern "C" void kernel_launch(void* const* d_in, const int* in_sizes, int n_in,
                              void* d_out, int out_size, void* d_ws, size_t ws_size,
                              hipStream_t stream) {
  const float* x    = (const float*)d_in[0];
  const int*   mask = (const int*)d_in[1];
  const float* W1   = (const float*)d_in[2];
  const float* b1   = (const float*)d_in[3];
  const float* W2   = (const float*)d_in[4];
  const float* b2   = (const float*)d_in[5];
  const float* W3   = (const float*)d_in[6];
  const float* b3   = (const float*)d_in[7];
  const float* rW1  = (const float*)d_in[8];
  const float* rb1  = (const float*)d_in[9];
  const float* rW2  = (const float*)d_in[10];
  const float* rb2  = (const float*)d_in[11];
  const float* rW3  = (const float*)d_in[12];
  const float* rb3  = (const float*)d_in[13];
  float* out = (float*)d_out;
  f16_t* ws = (f16_t*)d_ws;

  convert_weights<<<256, 256, 0, stream>>>(W1, b1, W2, W3, b3, rW1, rW2, rW3, ws);
  indexnet_main<<<NROWS / 128, 512, 0, stream>>>(
      x, mask, b2, rb1, rb2, rb3, ws, out);
}

// Round 12
// 62.599 us; speedup vs baseline: 1.1917x; 1.1917x over previous
//
#include <hip/hip_runtime.h>
#include <hip/hip_bf16.h>
#include <math.h>

typedef _Float16 f16_t;
typedef _Float16 f16x8 __attribute__((ext_vector_type(8)));
typedef float f32x16 __attribute__((ext_vector_type(16)));
typedef unsigned int uintx4 __attribute__((ext_vector_type(4)));
typedef unsigned int uintx2 __attribute__((ext_vector_type(2)));

#define NROWS 32768
#define DD 32
#define SIG_OFF (NROWS * 64)

// ---------------- ws layout (f16 elements) ----------------
// GEMM weights in PER-WAVE FRAGMENT-LOAD ORDER: [tile][ks][lane][j(0..7)],
// lane = l31 + 32*lh; n = tile*32 + l31; k = ks*16 + lh*8 + j.
// Per-d superblock: wf2(4096) | wf3(8192) = 12288 f16 = 24KB.
#define PERD_STRIDE 12288
#define W1B1F_OFF  393216          // [32 d][128] : w1[0..63] | b1[64..127]
#define RW1F_OFF   397312          // 2t x 8ks x 512 (rW1[k][n], k<128)
#define RW2F_OFF   405504          // 2t x 4ks x 512 (rW2[k][n], k<64)
#define RW3F_OFF   409600          // 4nt x 4ks x 512 (rW3[k][n], n<128)
#define B3F_OFF    417792          // 4t x 2ks x 512 (b3[d][n] as B-frag, "k"=d)
#define WS_ELEMS   421888

__global__ void convert_weights(const float* __restrict__ W1,
                                const float* __restrict__ b1,
                                const float* __restrict__ W2,
                                const float* __restrict__ W3,
                                const float* __restrict__ b3,
                                const float* __restrict__ rW1,
                                const float* __restrict__ rW2,
                                const float* __restrict__ rW3,
                                f16_t* __restrict__ ws) {
  for (int i = blockIdx.x * blockDim.x + threadIdx.x; i < WS_ELEMS;
       i += gridDim.x * blockDim.x) {
    float v;
    if (i < W1B1F_OFF) {
      int d = i / PERD_STRIDE;
      int r = i - d * PERD_STRIDE;
      if (r < 4096) {                 // wf2 fragments: W2[d][k][n], n<64
        int t = r >> 11, ks = (r >> 9) & 3, lane = (r >> 3) & 63, j = r & 7;
        int n = t * 32 + (lane & 31);
        int k = ks * 16 + (lane >> 5) * 8 + j;
        v = W2[(d * 64 + k) * 64 + n];
      } else {                        // wf3 fragments: W3[d][k][n], n<128
        int r2 = r - 4096;
        int t = r2 >> 11, ks = (r2 >> 9) & 3, lane = (r2 >> 3) & 63, j = r2 & 7;
        int n = t * 32 + (lane & 31);
        int k = ks * 16 + (lane >> 5) * 8 + j;
        v = W3[(d * 64 + k) * 128 + n];
      }
    } else if (i < RW1F_OFF) {        // w1 | b1, [d][128]
      int jj = i - W1B1F_OFF;
      int d = jj >> 7, c = jj & 127;
      v = (c < 64) ? W1[d * 64 + c] : b1[d * 64 + (c - 64)];
    } else if (i < RW2F_OFF) {        // rW1 fragments, k<128
      int i2 = i - RW1F_OFF;
      int t = i2 >> 12, ks = (i2 >> 9) & 7, lane = (i2 >> 3) & 63, j = i2 & 7;
      int n = t * 32 + (lane & 31);
      int k = ks * 16 + (lane >> 5) * 8 + j;
      v = rW1[k * 64 + n];
    } else if (i < RW3F_OFF) {        // rW2 fragments, k<64
      int i2 = i - RW2F_OFF;
      int t = i2 >> 11, ks = (i2 >> 9) & 3, lane = (i2 >> 3) & 63, j = i2 & 7;
      int n = t * 32 + (lane & 31);
      int k = ks * 16 + (lane >> 5) * 8 + j;
      v = rW2[k * 64 + n];
    } else if (i < B3F_OFF) {         // rW3 fragments, output col n<128, k<64
      int i2 = i - RW3F_OFF;
      int nt = i2 >> 11, ks = (i2 >> 9) & 3, lane = (i2 >> 3) & 63, j = i2 & 7;
      int n = nt * 32 + (lane & 31);
      int k = ks * 16 + (lane >> 5) * 8 + j;
      v = rW3[k * 128 + n];
    } else {                          // b3 as B-fragment: "k" axis = d (32)
      int i2 = i - B3F_OFF;
      int t = i2 >> 10, ks = (i2 >> 9) & 1, lane = (i2 >> 3) & 63, j = i2 & 7;
      int n = t * 32 + (lane & 31);
      int dsrc = ks * 16 + (lane >> 5) * 8 + j;
      v = b3[dsrc * 128 + n];
    }
    ws[i] = (f16_t)v;
  }
}

// Swapped-C tile (lane = data-row l31, regs: n=(reg&3)+8*(reg>>2)+4*lh) ->
// two B fragments via a PER-WAVE private LDS round-trip (no barrier; the
// within-wave ds_write->ds_read dependence is compiler-ordered).
__device__ __forceinline__ void xpose2(const f32x16& c, unsigned* row, int lh,
                                       f16x8& o0, f16x8& o1) {
  #pragma unroll
  for (int a = 0; a < 4; ++a) {
    uintx2 w;
    w.x = __builtin_bit_cast(unsigned, __builtin_amdgcn_cvt_pkrtz(c[4 * a + 0], c[4 * a + 1]));
    w.y = __builtin_bit_cast(unsigned, __builtin_amdgcn_cvt_pkrtz(c[4 * a + 2], c[4 * a + 3]));
    *reinterpret_cast<uintx2*>(row + 4 * a + 2 * lh) = w;
  }
  uintx2 ra = *reinterpret_cast<const uintx2*>(row + 4 * lh);
  uintx2 rb = *reinterpret_cast<const uintx2*>(row + 4 * lh + 2);
  uintx2 rc = *reinterpret_cast<const uintx2*>(row + 8 + 4 * lh);
  uintx2 rd = *reinterpret_cast<const uintx2*>(row + 8 + 4 * lh + 2);
  uintx4 w0 = {ra.x, ra.y, rb.x, rb.y};
  uintx4 w1 = {rc.x, rc.y, rd.x, rd.y};
  o0 = __builtin_bit_cast(f16x8, w0);
  o1 = __builtin_bit_cast(f16x8, w1);
}

// Stage next d of all 4 streams: direct global->LDS DMA, NO VGPR round-trip
// (r11 post-mortem: reg-staging's 48-VGPR spike caused 63MB of scratch spill).
// Wave wid covers 12KB = half of stream (wid>>1); dest = uniform base + c*1KB,
// HW adds lane*16. Layout is linear on both sides. Drain: the following
// __syncthreads() emits s_waitcnt vmcnt(0) (m97-verified compiler behavior).
__device__ __forceinline__ void stage_streams(const f16_t* __restrict__ ws,
                                              f16_t* __restrict__ wflat,
                                              int wid, int lane, int di) {
  const int s = wid >> 1;
  const f16_t* src = ws + (size_t)(s * 8 + di) * PERD_STRIDE
                     + (wid & 1) * 6144 + lane * 8;
  f16_t* dst = wflat + wid * 6144;
  #pragma unroll
  for (int c = 0; c < 12; ++c) {
    __builtin_amdgcn_global_load_lds(
        (const __attribute__((address_space(1))) void*)(src + c * 512),
        (__attribute__((address_space(3))) void*)(dst + c * 512), 16, 0, 0);
  }
}

// Readout chain for one 32-row subtile (pooled acc -> mu | softplus(sigma)).
__device__ __forceinline__ void readout32(f32x16* acc, unsigned mword,
                                          const f16_t* __restrict__ ws,
                                          const float* __restrict__ rb,
                                          unsigned* xr0, unsigned* xr1,
                                          int lane16, int l31, int lh,
                                          int rowb, float* __restrict__ out) {
  // ---- pooled += maskT @ b3 (bias of masked sum), 8 MFMA ----
  {
    f16x8 mf[2];
    #pragma unroll
    for (int ks = 0; ks < 2; ++ks) {
      unsigned w[4];
      #pragma unroll
      for (int ii = 0; ii < 4; ++ii) {
        int d0 = ks * 16 + lh * 8 + 2 * ii;
        w[ii] = (((mword >> d0) & 1u) ? 0x3C00u : 0u) |
                (((mword >> (d0 + 1)) & 1u) ? 0x3C000000u : 0u);
      }
      uintx4 ww = {w[0], w[1], w[2], w[3]};
      mf[ks] = __builtin_bit_cast(f16x8, ww);
    }
    const f16_t* b3f = ws + B3F_OFF;
    #pragma unroll
    for (int t = 0; t < 4; ++t)
      #pragma unroll
      for (int ks = 0; ks < 2; ++ks) {
        f16x8 bf = *reinterpret_cast<const f16x8*>(b3f + (t * 2 + ks) * 512 + lane16);
        acc[t] = __builtin_amdgcn_mfma_f32_32x32x16_f16(bf, mf[ks], acc[t], 0, 0, 0);
      }
  }
  // ---- R1 (swapped): r1^T = rW1T x pooled^T, K=128 ----
  f16x8 poolf[8];
  xpose2(acc[0], xr0, lh, poolf[0], poolf[1]);
  xpose2(acc[1], xr1, lh, poolf[2], poolf[3]);
  xpose2(acc[2], xr0, lh, poolf[4], poolf[5]);
  xpose2(acc[3], xr1, lh, poolf[6], poolf[7]);
  f32x16 r1[2];
  #pragma unroll
  for (int t = 0; t < 2; ++t)
    #pragma unroll
    for (int a = 0; a < 4; ++a) {
      float4 bv = *reinterpret_cast<const float4*>(&rb[t * 32 + a * 8 + lh * 4]);
      r1[t][4 * a + 0] = bv.x; r1[t][4 * a + 1] = bv.y;
      r1[t][4 * a + 2] = bv.z; r1[t][4 * a + 3] = bv.w;
    }
  {
    const f16_t* rw1 = ws + RW1F_OFF;
    #pragma unroll
    for (int t = 0; t < 2; ++t)
      #pragma unroll
      for (int ks = 0; ks < 8; ++ks) {
        f16x8 wf = *reinterpret_cast<const f16x8*>(rw1 + (t * 8 + ks) * 512 + lane16);
        r1[t] = __builtin_amdgcn_mfma_f32_32x32x16_f16(wf, poolf[ks], r1[t], 0, 0, 0);
      }
  }
  #pragma unroll
  for (int t = 0; t < 2; ++t)
    #pragma unroll
    for (int r = 0; r < 16; ++r) r1[t][r] = fmaxf(r1[t][r], 0.f);

  // ---- R2 (swapped): r2^T = rW2T x r1^T, K=64 ----
  f16x8 r1f[4];
  xpose2(r1[0], xr0, lh, r1f[0], r1f[1]);
  xpose2(r1[1], xr1, lh, r1f[2], r1f[3]);
  f32x16 r2[2];
  #pragma unroll
  for (int t = 0; t < 2; ++t)
    #pragma unroll
    for (int a = 0; a < 4; ++a) {
      float4 bv = *reinterpret_cast<const float4*>(&rb[64 + t * 32 + a * 8 + lh * 4]);
      r2[t][4 * a + 0] = bv.x; r2[t][4 * a + 1] = bv.y;
      r2[t][4 * a + 2] = bv.z; r2[t][4 * a + 3] = bv.w;
    }
  {
    const f16_t* rw2 = ws + RW2F_OFF;
    #pragma unroll
    for (int t = 0; t < 2; ++t)
      #pragma unroll
      for (int ks = 0; ks < 4; ++ks) {
        f16x8 wf = *reinterpret_cast<const f16x8*>(rw2 + (t * 4 + ks) * 512 + lane16);
        r2[t] = __builtin_amdgcn_mfma_f32_32x32x16_f16(wf, r1f[ks], r2[t], 0, 0, 0);
      }
  }
  #pragma unroll
  for (int t = 0; t < 2; ++t)
    #pragma unroll
    for (int r = 0; r < 16; ++r) r2[t][r] = fmaxf(r2[t][r], 0.f);

  // ---- R3 (NON-swapped for coalesced stores): o = r2 @ rW3, N=128 ----
  f16x8 r2f[4];
  xpose2(r2[0], xr0, lh, r2f[0], r2f[1]);
  xpose2(r2[1], xr1, lh, r2f[2], r2f[3]);
  f32x16 oacc[4] = {};
  {
    const f16_t* rw3 = ws + RW3F_OFF;
    #pragma unroll
    for (int nt = 0; nt < 4; ++nt)
      #pragma unroll
      for (int ks = 0; ks < 4; ++ks) {
        f16x8 wf = *reinterpret_cast<const f16x8*>(rw3 + (nt * 4 + ks) * 512 + lane16);
        oacc[nt] = __builtin_amdgcn_mfma_f32_32x32x16_f16(r2f[ks], wf, oacc[nt], 0, 0, 0);
      }
  }
  #pragma unroll
  for (int nt = 0; nt < 4; ++nt) {
    float rbv = rb[128 + nt * 32 + l31];
    #pragma unroll
    for (int r = 0; r < 16; ++r) {
      int rl = (r & 3) + 8 * (r >> 2) + 4 * lh;
      size_t grow = (size_t)(rowb + rl);
      float v = oacc[nt][r] + rbv;
      if (nt < 2) {
        out[grow * 64 + nt * 32 + l31] = v;
      } else {
        float sp = fmaxf(v, 0.f) + __logf(1.f + __expf(-fabsf(v)));
        out[(size_t)SIG_OFF + grow * 64 + (nt - 2) * 32 + l31] = sp;
      }
    }
  }
}

// Round 12 = round 11 geometry, spill-free. Block = 512 thr = 8 waves.
// Wave (pr = wid>>2, q = wid&3): pr owns 64 rows (2 subtiles), q owns the
// d-quarter [8q, 8q+8). 4 single-buffered 24KB streams. One wf2/wf3 LDS
// fragment read feeds TWO MFMAs (64 rows) -- halves the dominant LDS term.
// VGPR discipline (non-acc live set <= ~120 so accA/accB's 128 AGPRs fit
// the 256 unified cap at 2 waves/SIMD):
//   (1) staging via global_load_lds (no 48-reg register round-trip),
//   (2) per-t fused GEMM1 -> xpose -> GEMM2-ks-half (pf window 16 not 32),
//   (3) scalar x loads, #pragma unroll 1 on the d-loop.
__launch_bounds__(512, 2)
__global__ void indexnet_main(const float* __restrict__ x,
                              const int* __restrict__ mask,
                              const float* __restrict__ b2,
                              const float* __restrict__ rb1,
                              const float* __restrict__ rb2,
                              const float* __restrict__ rb3,
                              const f16_t* __restrict__ ws,
                              float* __restrict__ out) {
  __shared__ __align__(16) f16_t wbuf[4][12288];       // 96KB: 4 q-streams
  __shared__ __align__(16) f16_t w1b1_lds[32][128];    // 8KB
  __shared__ float b2_lds[32][64];                     // 8KB
  __shared__ float rb_lds[256];                        // 1KB
  __shared__ __align__(16) unsigned xp_lds[8][2][32][18];  // 36.9KB
  // total 150.5KB -> 1 block/CU, 8 waves/CU = 2 waves/SIMD

  const int tid = threadIdx.x;
  const int lane = tid & 63;
  const int wid = tid >> 6;
  const int pr = wid >> 2;         // row group (0..1), 64 rows each
  const int q = wid & 3;           // d-quarter
  const int l31 = lane & 31;
  const int lh = lane >> 5;
  const int row0 = blockIdx.x * 128;
  const int lane16 = lane * 8;

  unsigned* xr0 = &xp_lds[wid][0][l31][0];
  unsigned* xr1 = &xp_lds[wid][1][l31][0];

  // ---- stage b2 [32][64] f32 (512 x float4) ----
  {
    float4* dst = reinterpret_cast<float4*>(&b2_lds[0][0]);
    const float4* src = reinterpret_cast<const float4*>(b2);
    dst[tid] = src[tid];
  }
  // ---- stage readout biases ----
  if (tid < 64)        rb_lds[tid] = rb1[tid];
  else if (tid < 128)  rb_lds[tid] = rb2[tid - 64];
  else if (tid < 256)  rb_lds[tid] = rb3[tid - 128];
  // ---- stage w1|b1 [32][128] f16 (512 x 16B) ----
  {
    const uintx4* src = reinterpret_cast<const uintx4*>(ws + W1B1F_OFF);
    uintx4* dst = reinterpret_cast<uintx4*>(&w1b1_lds[0][0]);
    dst[tid] = src[tid];
  }
  // ---- per-lane mask words for BOTH own rows ----
  unsigned mwordA = 0, mwordB = 0;
  {
    const int4* mrA = reinterpret_cast<const int4*>(mask + (size_t)(row0 + pr * 64 + l31) * DD);
    const int4* mrB = reinterpret_cast<const int4*>(mask + (size_t)(row0 + pr * 64 + 32 + l31) * DD);
    #pragma unroll
    for (int c4 = 0; c4 < 8; ++c4) {
      int4 a = mrA[c4];
      int4 b = mrB[c4];
      mwordA |= (a.x != 0 ? 1u : 0u) << (4 * c4);
      mwordA |= (a.y != 0 ? 1u : 0u) << (4 * c4 + 1);
      mwordA |= (a.z != 0 ? 1u : 0u) << (4 * c4 + 2);
      mwordA |= (a.w != 0 ? 1u : 0u) << (4 * c4 + 3);
      mwordB |= (b.x != 0 ? 1u : 0u) << (4 * c4);
      mwordB |= (b.y != 0 ? 1u : 0u) << (4 * c4 + 1);
      mwordB |= (b.z != 0 ? 1u : 0u) << (4 * c4 + 2);
      mwordB |= (b.w != 0 ? 1u : 0u) << (4 * c4 + 3);
    }
  }
  const int qbase = q * 8;
  const float* xrowA = x + (size_t)(row0 + pr * 64 + l31) * DD + qbase;
  const float* xrowB = x + (size_t)(row0 + pr * 64 + 32 + l31) * DD + qbase;

  // ---- prologue: DMA d = {0,8,16,24} into the 4 streams ----
  stage_streams(ws, &wbuf[0][0], wid, lane, 0);
  __syncthreads();   // drains vmcnt -> streams + b2/rb/w1b1 ready

  f32x16 accA[4] = {}, accB[4] = {};

  #pragma unroll 1
  for (int i = 0; i < 8; ++i) {
    const int d = qbase + i;
    float xvA = xrowA[i];
    float xvB = xrowB[i];

    // ---- h1 fragments for both subtiles ----
    f16x8 h1fA[4], h1fB[4];
    {
      f16_t xhA = (f16_t)xvA, xhB = (f16_t)xvB;
      f16x8 xA8 = {xhA, xhA, xhA, xhA, xhA, xhA, xhA, xhA};
      f16x8 xB8 = {xhB, xhB, xhB, xhB, xhB, xhB, xhB, xhB};
      #pragma unroll
      for (int ks = 0; ks < 4; ++ks) {
        f16x8 w1 = *reinterpret_cast<const f16x8*>(&w1b1_lds[d][ks * 16 + lh * 8]);
        f16x8 bb = *reinterpret_cast<const f16x8*>(&w1b1_lds[d][64 + ks * 16 + lh * 8]);
        h1fA[ks] = __builtin_elementwise_max(xA8 * w1 + bb, (f16x8)(f16_t)0);
        h1fB[ks] = __builtin_elementwise_max(xB8 * w1 + bb, (f16x8)(f16_t)0);
      }
    }

    const f16_t* wb = &wbuf[q][0];
    const bool mA = (mwordA >> d) & 1u;
    const bool mB = (mwordB >> d) & 1u;

    // ---- per-t fused GEMM1 -> xpose -> GEMM2 ks-half ----
    #pragma unroll
    for (int t = 0; t < 2; ++t) {
      f16x8 wf2t[4];
      #pragma unroll
      for (int ks = 0; ks < 4; ++ks)
        wf2t[ks] = *reinterpret_cast<const f16x8*>(wb + (t * 4 + ks) * 512 + lane16);
      f32x16 haccA, haccB;
      #pragma unroll
      for (int a = 0; a < 4; ++a) {
        float4 bv = *reinterpret_cast<const float4*>(&b2_lds[d][t * 32 + a * 8 + lh * 4]);
        haccA[4 * a + 0] = bv.x; haccA[4 * a + 1] = bv.y;
        haccA[4 * a + 2] = bv.z; haccA[4 * a + 3] = bv.w;
        haccB[4 * a + 0] = bv.x; haccB[4 * a + 1] = bv.y;
        haccB[4 * a + 2] = bv.z; haccB[4 * a + 3] = bv.w;
      }
      #pragma unroll
      for (int ks = 0; ks < 4; ++ks) {
        haccA = __builtin_amdgcn_mfma_f32_32x32x16_f16(wf2t[ks], h1fA[ks], haccA, 0, 0, 0);
        haccB = __builtin_amdgcn_mfma_f32_32x32x16_f16(wf2t[ks], h1fB[ks], haccB, 0, 0, 0);
      }
      #pragma unroll
      for (int r = 0; r < 16; ++r) {
        float vA = fmaxf(haccA[r], 0.f);
        float vB = fmaxf(haccB[r], 0.f);
        haccA[r] = mA ? vA : 0.f;
        haccB[r] = mB ? vB : 0.f;
      }
      f16x8 pA0, pA1, pB0, pB1;
      xpose2(haccA, xr0, lh, pA0, pA1);
      xpose2(haccB, xr1, lh, pB0, pB1);
      // GEMM2 partial: k-slices 2t, 2t+1 for all 4 output tiles
      #pragma unroll
      for (int tt = 0; tt < 4; ++tt) {
        f16x8 w3a = *reinterpret_cast<const f16x8*>(wb + 4096 + (tt * 4 + 2 * t) * 512 + lane16);
        f16x8 w3b = *reinterpret_cast<const f16x8*>(wb + 4096 + (tt * 4 + 2 * t + 1) * 512 + lane16);
        accA[tt] = __builtin_amdgcn_mfma_f32_32x32x16_f16(w3a, pA0, accA[tt], 0, 0, 0);
        accA[tt] = __builtin_amdgcn_mfma_f32_32x32x16_f16(w3b, pA1, accA[tt], 0, 0, 0);
        accB[tt] = __builtin_amdgcn_mfma_f32_32x32x16_f16(w3a, pB0, accB[tt], 0, 0, 0);
        accB[tt] = __builtin_amdgcn_mfma_f32_32x32x16_f16(w3b, pB1, accB[tt], 0, 0, 0);
      }
    }

    // ---- refill all 4 streams with next d (DMA, no VGPRs) ----
    __syncthreads();   // all waves done reading current superblocks
    if (i < 7)
      stage_streams(ws, &wbuf[0][0], wid, lane, i + 1);
    __syncthreads();   // drains vmcnt -> new superblocks visible
  }

  // ---- pool combine across the 4 q-quarters (aliased onto dead wbuf) ----
  float4* pool4 = reinterpret_cast<float4*>(&wbuf[0][0]);
  #pragma unroll 1
  for (int qq = 1; qq <= 3; ++qq) {
    if (q == qq) {
      #pragma unroll
      for (int sub = 0; sub < 2; ++sub) {
        f32x16* acc = sub ? accB : accA;
        #pragma unroll
        for (int t = 0; t < 4; ++t) {
          int ci = ((pr * 2 + sub) * 4 + t) * 2 + lh;
          #pragma unroll
          for (int a = 0; a < 4; ++a) {
            float4 f = {acc[t][4 * a], acc[t][4 * a + 1],
                        acc[t][4 * a + 2], acc[t][4 * a + 3]};
            pool4[(ci * 4 + a) * 32 + l31] = f;
          }
        }
      }
    }
    __syncthreads();
    if (q == 0) {
      #pragma unroll
      for (int sub = 0; sub < 2; ++sub) {
        f32x16* acc = sub ? accB : accA;
        #pragma unroll
        for (int t = 0; t < 4; ++t) {
          int ci = ((pr * 2 + sub) * 4 + t) * 2 + lh;
          #pragma unroll
          for (int a = 0; a < 4; ++a) {
            float4 f = pool4[(ci * 4 + a) * 32 + l31];
            acc[t][4 * a + 0] += f.x; acc[t][4 * a + 1] += f.y;
            acc[t][4 * a + 2] += f.z; acc[t][4 * a + 3] += f.w;
          }
        }
      }
    }
    __syncthreads();
  }
  if (q != 0) return;

  // ---- readout: q0 waves handle both subtiles of their 64 rows ----
  readout32(accA, mwordA, ws, rb_lds, xr0, xr1, lane16, l31, lh,
            row0 + pr * 64, out);
  readout32(accB, mwordB, ws, rb_lds, xr0, xr1, lane16, l31, lh,
            row0 + pr * 64 + 32, out);
}

extern "C" void kernel_launch(void* const* d_in, const int* in_sizes, int n_in,
                              void* d_out, int out_size, void* d_ws, size_t ws_size,
                              hipStream_t stream) {
  const float* x    = (const float*)d_in[0];
  const int*   mask = (const int*)d_in[1];
  const float* W1   = (const float*)d_in[2];
  const float* b1   = (const float*)d_in[3];
  const float* W2   = (const float*)d_in[4];
  const float* b2   = (const float*)d_in[5];
  const float* W3   = (const float*)d_in[6];
  const float* b3   = (const float*)d_in[7];
  const float* rW1  = (const float*)d_in[8];
  const float* rb1  = (const float*)d_in[9];
  const float* rW2  = (const float*)d_in[10];
  const float* rb2  = (const float*)d_in[11];
  const float* rW3  = (const float*)d_in[12];
  const float* rb3  = (const float*)d_in[13];
  float* out = (float*)d_out;
  f16_t* ws = (f16_t*)d_ws;

  convert_weights<<<256, 256, 0, stream>>>(W1, b1, W2, W3, b3, rW1, rW2, rW3, ws);
  indexnet_main<<<NROWS / 128, 512, 0, stream>>>(
      x, mask, b2, rb1, rb2, rb3, ws, out);
}

// Round 13
// 50.280 us; speedup vs baseline: 1.4837x; 1.2450x over previous
//
#include <hip/hip_runtime.h>
#include <hip/hip_bf16.h>
#include <math.h>

typedef _Float16 f16_t;
typedef _Float16 f16x8 __attribute__((ext_vector_type(8)));
typedef float f32x16 __attribute__((ext_vector_type(16)));
typedef unsigned int uintx4 __attribute__((ext_vector_type(4)));
typedef unsigned int uintx2 __attribute__((ext_vector_type(2)));

#define NROWS 32768
#define DD 32
#define SIG_OFF (NROWS * 64)

// ---------------- ws layout (f16 elements) ----------------
// Fragment order: [tile][ks][lane][j], n = t*32+(lane&31), k = ks*16+(lane>>5)*8+j.
// Per-d superblock (K=80 GEMM1 with b2 folded as the k=64 row):
//   wf2ext: 2t x 5ks x 512 = 5120  (ks=4 fragment: (lh==0&&j==0) ? b2[d][n] : 0)
//   wf3   : 4t x 4ks x 512 = 8192
#define PERD_STRIDE 13312
#define SB_LDS      14336          // staged size/d (28KB; overreads 2KB, harmless)
#define W1B1F_OFF   425984         // 32*13312; [32 d][128]: w1|b1
#define RW1F_OFF    430080
#define RW2F_OFF    438272
#define RW3F_OFF    442368
#define B3F_OFF     450560
#define WS_ELEMS    454656

__global__ void convert_weights(const float* __restrict__ W1,
                                const float* __restrict__ b1,
                                const float* __restrict__ W2,
                                const float* __restrict__ b2,
                                const float* __restrict__ W3,
                                const float* __restrict__ b3,
                                const float* __restrict__ rW1,
                                const float* __restrict__ rW2,
                                const float* __restrict__ rW3,
                                f16_t* __restrict__ ws) {
  for (int i = blockIdx.x * blockDim.x + threadIdx.x; i < WS_ELEMS;
       i += gridDim.x * blockDim.x) {
    float v;
    if (i < W1B1F_OFF) {
      int d = i / PERD_STRIDE;
      int r = i - d * PERD_STRIDE;
      if (r < 5120) {                 // wf2ext: K=80 (ks=4 row = b2)
        int t = r / 2560, rr = r - t * 2560;
        int ks = rr >> 9, lane = (rr >> 3) & 63, j = rr & 7;
        int n = t * 32 + (lane & 31);
        if (ks < 4) {
          int k = ks * 16 + (lane >> 5) * 8 + j;
          v = W2[(d * 64 + k) * 64 + n];
        } else {
          v = ((lane >> 5) == 0 && j == 0) ? b2[d * 64 + n] : 0.f;
        }
      } else {                        // wf3: W3[d][k][n], n<128
        int r2 = r - 5120;
        int t = r2 >> 11, ks = (r2 >> 9) & 3, lane = (r2 >> 3) & 63, j = r2 & 7;
        int n = t * 32 + (lane & 31);
        int k = ks * 16 + (lane >> 5) * 8 + j;
        v = W3[(d * 64 + k) * 128 + n];
      }
    } else if (i < RW1F_OFF) {        // w1 | b1, [d][128]
      int jj = i - W1B1F_OFF;
      int d = jj >> 7, c = jj & 127;
      v = (c < 64) ? W1[d * 64 + c] : b1[d * 64 + (c - 64)];
    } else if (i < RW2F_OFF) {        // rW1 fragments, k<128
      int i2 = i - RW1F_OFF;
      int t = i2 >> 12, ks = (i2 >> 9) & 7, lane = (i2 >> 3) & 63, j = i2 & 7;
      int n = t * 32 + (lane & 31);
      int k = ks * 16 + (lane >> 5) * 8 + j;
      v = rW1[k * 64 + n];
    } else if (i < RW3F_OFF) {        // rW2 fragments, k<64
      int i2 = i - RW2F_OFF;
      int t = i2 >> 11, ks = (i2 >> 9) & 3, lane = (i2 >> 3) & 63, j = i2 & 7;
      int n = t * 32 + (lane & 31);
      int k = ks * 16 + (lane >> 5) * 8 + j;
      v = rW2[k * 64 + n];
    } else if (i < B3F_OFF) {         // rW3 fragments, output col n<128, k<64
      int i2 = i - RW3F_OFF;
      int nt = i2 >> 11, ks = (i2 >> 9) & 3, lane = (i2 >> 3) & 63, j = i2 & 7;
      int n = nt * 32 + (lane & 31);
      int k = ks * 16 + (lane >> 5) * 8 + j;
      v = rW3[k * 128 + n];
    } else {                          // b3 as B-fragment: "k" axis = d (32)
      int i2 = i - B3F_OFF;
      int t = i2 >> 10, ks = (i2 >> 9) & 1, lane = (i2 >> 3) & 63, j = i2 & 7;
      int n = t * 32 + (lane & 31);
      int dsrc = ks * 16 + (lane >> 5) * 8 + j;
      v = b3[dsrc * 128 + n];
    }
    ws[i] = (f16_t)v;
  }
}

// REGISTER-ONLY transpose of a swapped-GEMM C tile into two B fragments.
// Lane L holds n = (reg&3)+8*(reg>>2)+4*lh for its data row (lanes L, L+32 =
// same row, n offset by 4). Target: lane supplies n = 16*kk + 8*lh + j.
// v_permlane32_swap_b32 (vdst.row1 <-> vsrc.row0) on the cvt_pk'd pairs is
// exactly the needed 2x2 row-block transpose: swap(pk(c0,c1), pk(c4,c5))
// yields {words 0,2} of the fragment; second swap yields {words 1,3}.
__device__ __forceinline__ void xpose2r(const f32x16& c, f16x8& o0, f16x8& o1) {
  unsigned u0 = __builtin_bit_cast(unsigned, __builtin_amdgcn_cvt_pkrtz(c[0], c[1]));
  unsigned u1 = __builtin_bit_cast(unsigned, __builtin_amdgcn_cvt_pkrtz(c[2], c[3]));
  unsigned v0 = __builtin_bit_cast(unsigned, __builtin_amdgcn_cvt_pkrtz(c[4], c[5]));
  unsigned v1 = __builtin_bit_cast(unsigned, __builtin_amdgcn_cvt_pkrtz(c[6], c[7]));
  uintx2 s0 = __builtin_amdgcn_permlane32_swap(u0, v0, false, false);
  uintx2 s1 = __builtin_amdgcn_permlane32_swap(u1, v1, false, false);
  uintx4 w0 = {s0.x, s1.x, s0.y, s1.y};
  o0 = __builtin_bit_cast(f16x8, w0);
  unsigned u2 = __builtin_bit_cast(unsigned, __builtin_amdgcn_cvt_pkrtz(c[8], c[9]));
  unsigned u3 = __builtin_bit_cast(unsigned, __builtin_amdgcn_cvt_pkrtz(c[10], c[11]));
  unsigned v2 = __builtin_bit_cast(unsigned, __builtin_amdgcn_cvt_pkrtz(c[12], c[13]));
  unsigned v3 = __builtin_bit_cast(unsigned, __builtin_amdgcn_cvt_pkrtz(c[14], c[15]));
  uintx2 s2 = __builtin_amdgcn_permlane32_swap(u2, v2, false, false);
  uintx2 s3 = __builtin_amdgcn_permlane32_swap(u3, v3, false, false);
  uintx4 w1 = {s2.x, s3.x, s2.y, s3.y};
  o1 = __builtin_bit_cast(f16x8, w1);
}

// One d-iteration: h1 -> GEMM1 (swapped, K=80 with b2 folded) -> relu/mask ->
// register xpose -> GEMM2 (swapped, accumulate into pooled acc).
__device__ __forceinline__ void compute_d(const f16_t* __restrict__ wb,
                                          const f16_t* __restrict__ w1b1row,
                                          float xv, bool mb,
                                          int lane16, int lh, f32x16* acc) {
  f16x8 wf2[2][5], wf3[4][4];
  #pragma unroll
  for (int t = 0; t < 2; ++t)
    #pragma unroll
    for (int ks = 0; ks < 5; ++ks)
      wf2[t][ks] = *reinterpret_cast<const f16x8*>(wb + (t * 5 + ks) * 512 + lane16);
  #pragma unroll
  for (int t = 0; t < 4; ++t)
    #pragma unroll
    for (int ks = 0; ks < 4; ++ks)
      wf3[t][ks] = *reinterpret_cast<const f16x8*>(wb + 5120 + (t * 4 + ks) * 512 + lane16);

  f16_t xh = (f16_t)xv;
  f16x8 xv8 = {xh, xh, xh, xh, xh, xh, xh, xh};
  f16x8 h1f[5];
  #pragma unroll
  for (int ks = 0; ks < 4; ++ks) {
    f16x8 w1 = *reinterpret_cast<const f16x8*>(w1b1row + ks * 16 + lh * 8);
    f16x8 bb = *reinterpret_cast<const f16x8*>(w1b1row + 64 + ks * 16 + lh * 8);
    f16x8 h = xv8 * w1 + bb;
    h1f[ks] = __builtin_elementwise_max(h, (f16x8)(f16_t)0);
  }
  h1f[4] = (f16x8)(f16_t)0;
  h1f[4][0] = (lh == 0) ? (f16_t)1.0f : (f16_t)0.0f;  // h1_ext[k=64] = 1

  f32x16 hacc[2] = {};   // b2 arrives via the ks=4 MFMA
  #pragma unroll
  for (int ks = 0; ks < 5; ++ks) {
    hacc[0] = __builtin_amdgcn_mfma_f32_32x32x16_f16(wf2[0][ks], h1f[ks], hacc[0], 0, 0, 0);
    hacc[1] = __builtin_amdgcn_mfma_f32_32x32x16_f16(wf2[1][ks], h1f[ks], hacc[1], 0, 0, 0);
  }
  #pragma unroll
  for (int t = 0; t < 2; ++t)
    #pragma unroll
    for (int r = 0; r < 16; ++r) {
      float v = fmaxf(hacc[t][r], 0.f);
      hacc[t][r] = mb ? v : 0.f;
    }
  f16x8 pf[4];
  xpose2r(hacc[0], pf[0], pf[1]);
  xpose2r(hacc[1], pf[2], pf[3]);
  #pragma unroll
  for (int t = 0; t < 4; ++t)
    #pragma unroll
    for (int ks = 0; ks < 4; ++ks)
      acc[t] = __builtin_amdgcn_mfma_f32_32x32x16_f16(wf3[t][ks], pf[ks], acc[t], 0, 0, 0);
}

// Stage one d-superblock (28KB incl. overread) of stream (wid&1): the 4 waves
// of that stream each DMA 7KB directly global->LDS (no VGPR round-trip; the
// next __syncthreads drains vmcnt -- validated r12).
__device__ __forceinline__ void stage_sb(const f16_t* __restrict__ ws,
                                         f16_t* __restrict__ dstbase,
                                         int wid, int lane, int d) {
  const int g = wid >> 1;   // wave index within the stream's 4-wave group
  const f16_t* src = ws + (size_t)d * PERD_STRIDE + g * 3584 + lane * 8;
  f16_t* dst = dstbase + g * 3584;
  #pragma unroll
  for (int c = 0; c < 7; ++c)
    __builtin_amdgcn_global_load_lds(
        (const __attribute__((address_space(1))) void*)(src + c * 512),
        (__attribute__((address_space(3))) void*)(dst + c * 512), 16, 0, 0);
}

// Readout chain for one 32-row subtile (pooled acc -> mu | softplus(sigma)).
__device__ __forceinline__ void readout32(f32x16* acc, unsigned mword,
                                          const f16_t* __restrict__ ws,
                                          const float* __restrict__ rb,
                                          int lane16, int l31, int lh,
                                          int rowb, float* __restrict__ out) {
  {
    f16x8 mf[2];
    #pragma unroll
    for (int ks = 0; ks < 2; ++ks) {
      unsigned w[4];
      #pragma unroll
      for (int ii = 0; ii < 4; ++ii) {
        int d0 = ks * 16 + lh * 8 + 2 * ii;
        w[ii] = (((mword >> d0) & 1u) ? 0x3C00u : 0u) |
                (((mword >> (d0 + 1)) & 1u) ? 0x3C000000u : 0u);
      }
      uintx4 ww = {w[0], w[1], w[2], w[3]};
      mf[ks] = __builtin_bit_cast(f16x8, ww);
    }
    const f16_t* b3f = ws + B3F_OFF;
    #pragma unroll
    for (int t = 0; t < 4; ++t)
      #pragma unroll
      for (int ks = 0; ks < 2; ++ks) {
        f16x8 bf = *reinterpret_cast<const f16x8*>(b3f + (t * 2 + ks) * 512 + lane16);
        acc[t] = __builtin_amdgcn_mfma_f32_32x32x16_f16(bf, mf[ks], acc[t], 0, 0, 0);
      }
  }
  f16x8 poolf[8];
  xpose2r(acc[0], poolf[0], poolf[1]);
  xpose2r(acc[1], poolf[2], poolf[3]);
  xpose2r(acc[2], poolf[4], poolf[5]);
  xpose2r(acc[3], poolf[6], poolf[7]);
  f32x16 r1[2];
  #pragma unroll
  for (int t = 0; t < 2; ++t)
    #pragma unroll
    for (int a = 0; a < 4; ++a) {
      float4 bv = *reinterpret_cast<const float4*>(&rb[t * 32 + a * 8 + lh * 4]);
      r1[t][4 * a + 0] = bv.x; r1[t][4 * a + 1] = bv.y;
      r1[t][4 * a + 2] = bv.z; r1[t][4 * a + 3] = bv.w;
    }
  {
    const f16_t* rw1 = ws + RW1F_OFF;
    #pragma unroll
    for (int t = 0; t < 2; ++t)
      #pragma unroll
      for (int ks = 0; ks < 8; ++ks) {
        f16x8 wf = *reinterpret_cast<const f16x8*>(rw1 + (t * 8 + ks) * 512 + lane16);
        r1[t] = __builtin_amdgcn_mfma_f32_32x32x16_f16(wf, poolf[ks], r1[t], 0, 0, 0);
      }
  }
  #pragma unroll
  for (int t = 0; t < 2; ++t)
    #pragma unroll
    for (int r = 0; r < 16; ++r) r1[t][r] = fmaxf(r1[t][r], 0.f);

  f16x8 r1f[4];
  xpose2r(r1[0], r1f[0], r1f[1]);
  xpose2r(r1[1], r1f[2], r1f[3]);
  f32x16 r2[2];
  #pragma unroll
  for (int t = 0; t < 2; ++t)
    #pragma unroll
    for (int a = 0; a < 4; ++a) {
      float4 bv = *reinterpret_cast<const float4*>(&rb[64 + t * 32 + a * 8 + lh * 4]);
      r2[t][4 * a + 0] = bv.x; r2[t][4 * a + 1] = bv.y;
      r2[t][4 * a + 2] = bv.z; r2[t][4 * a + 3] = bv.w;
    }
  {
    const f16_t* rw2 = ws + RW2F_OFF;
    #pragma unroll
    for (int t = 0; t < 2; ++t)
      #pragma unroll
      for (int ks = 0; ks < 4; ++ks) {
        f16x8 wf = *reinterpret_cast<const f16x8*>(rw2 + (t * 4 + ks) * 512 + lane16);
        r2[t] = __builtin_amdgcn_mfma_f32_32x32x16_f16(wf, r1f[ks], r2[t], 0, 0, 0);
      }
  }
  #pragma unroll
  for (int t = 0; t < 2; ++t)
    #pragma unroll
    for (int r = 0; r < 16; ++r) r2[t][r] = fmaxf(r2[t][r], 0.f);

  f16x8 r2f[4];
  xpose2r(r2[0], r2f[0], r2f[1]);
  xpose2r(r2[1], r2f[2], r2f[3]);
  f32x16 oacc[4] = {};
  {
    const f16_t* rw3 = ws + RW3F_OFF;
    #pragma unroll
    for (int nt = 0; nt < 4; ++nt)
      #pragma unroll
      for (int ks = 0; ks < 4; ++ks) {
        f16x8 wf = *reinterpret_cast<const f16x8*>(rw3 + (nt * 4 + ks) * 512 + lane16);
        oacc[nt] = __builtin_amdgcn_mfma_f32_32x32x16_f16(r2f[ks], wf, oacc[nt], 0, 0, 0);
      }
  }
  #pragma unroll
  for (int nt = 0; nt < 4; ++nt) {
    float rbv = rb[128 + nt * 32 + l31];
    #pragma unroll
    for (int r = 0; r < 16; ++r) {
      int rl = (r & 3) + 8 * (r >> 2) + 4 * lh;
      size_t grow = (size_t)(rowb + rl);
      float v = oacc[nt][r] + rbv;
      if (nt < 2) {
        out[grow * 64 + nt * 32 + l31] = v;
      } else {
        float sp = fmaxf(v, 0.f) + __logf(1.f + __expf(-fabsf(v)));
        out[(size_t)SIG_OFF + grow * 64 + (nt - 2) * 32 + l31] = sp;
      }
    }
  }
}

// Round 13 = round 10 base (proven 53us: 8 waves = 4 pr x 2 q, 32 rows/wave,
// 2 double-buffered LDS streams, 1 barrier/iter) + three additive cuts:
//  (1) register xpose via permlane32_swap builtin -- deletes xp_lds (37KB),
//      16 LDS ops/iter/wave, and the ds round-trip from the critical path;
//  (2) b2 folded into GEMM1 as K=80 -- deletes b2_lds and its reads;
//  (3) staging via global_load_lds DMA (validated r12) -- no VGPR round-trip.
__launch_bounds__(512, 2)
__global__ void indexnet_main(const float* __restrict__ x,
                              const int* __restrict__ mask,
                              const float* __restrict__ rb1,
                              const float* __restrict__ rb2,
                              const float* __restrict__ rb3,
                              const f16_t* __restrict__ ws,
                              float* __restrict__ out) {
  __shared__ __align__(16) f16_t wbuf[2][2][SB_LDS];   // [stream][dbuf] 112KB
  __shared__ __align__(16) f16_t w1b1_lds[32][128];    // 8KB
  __shared__ float rb_lds[256];                        // 1KB
  // total ~121KB -> 1 block/CU, 8 waves/CU = 2 waves/SIMD

  const int tid = threadIdx.x;
  const int lane = tid & 63;
  const int wid = tid >> 6;
  const int pr = wid >> 1;         // row group (0..3)
  const int q = wid & 1;           // d-half / stream
  const int l31 = lane & 31;
  const int lh = lane >> 5;
  const int row0 = blockIdx.x * 128;
  const int lane16 = lane * 8;

  // ---- stage readout biases ----
  if (tid < 64)        rb_lds[tid] = rb1[tid];
  else if (tid < 128)  rb_lds[tid] = rb2[tid - 64];
  else if (tid < 256)  rb_lds[tid] = rb3[tid - 128];
  // ---- stage w1|b1 [32][128] f16 (512 x 16B) ----
  {
    const uintx4* src = reinterpret_cast<const uintx4*>(ws + W1B1F_OFF);
    uintx4* dst = reinterpret_cast<uintx4*>(&w1b1_lds[0][0]);
    dst[tid] = src[tid];
  }
  // ---- per-lane mask word for own row ----
  unsigned mword = 0;
  {
    const int4* mrow = reinterpret_cast<const int4*>(mask + (size_t)(row0 + pr * 32 + l31) * DD);
    #pragma unroll
    for (int c4 = 0; c4 < 8; ++c4) {
      int4 m = mrow[c4];
      mword |= (m.x != 0 ? 1u : 0u) << (4 * c4);
      mword |= (m.y != 0 ? 1u : 0u) << (4 * c4 + 1);
      mword |= (m.z != 0 ? 1u : 0u) << (4 * c4 + 2);
      mword |= (m.w != 0 ? 1u : 0u) << (4 * c4 + 3);
    }
  }
  const float* xrow = x + (size_t)(row0 + pr * 32 + l31) * DD + q * 16;
  const int dbase = q * 16;

  // ---- prologue: DMA d=0 -> wbuf[0][0] (q0 waves), d=16 -> wbuf[1][0] ----
  stage_sb(ws, &wbuf[q][0][0], wid, lane, q * 16);
  __syncthreads();   // drains DMA; biases/w1b1 ready

  f32x16 acc[4] = {};   // pooled^T: tile t -> n = 32t + rl, lane = row

  for (int dd0 = 0; dd0 < 16; dd0 += 4) {
    float4 xv4 = *reinterpret_cast<const float4*>(xrow + dd0);
    #pragma unroll
    for (int j = 0; j < 4; ++j) {
      const int i = dd0 + j;
      const int d = dbase + i;
      // issue next-d DMA for this wave's stream into the other buffer
      if (i < 15)
        stage_sb(ws, &wbuf[q][(i + 1) & 1][0], wid, lane, dbase + i + 1);
      float xv = (j == 0) ? xv4.x : (j == 1) ? xv4.y : (j == 2) ? xv4.z : xv4.w;
      compute_d(&wbuf[q][i & 1][0], &w1b1_lds[d][0], xv,
                (mword >> d) & 1u, lane16, lh, acc);
      __syncthreads();   // drains DMA (vmcnt0) + publishes next buffer
    }
  }

  // ---- pool combine across q-halves (pool area aliases dead wbuf) ----
  float* pool_ex = reinterpret_cast<float*>(&wbuf[0][0][0]);
  float* prow = pool_ex + (((size_t)pr * 2 + lh) * 32 + l31) * 68;
  if (q == 1) {
    #pragma unroll
    for (int t = 0; t < 4; ++t)
      #pragma unroll
      for (int a = 0; a < 4; ++a) {
        float4 f = {acc[t][4 * a], acc[t][4 * a + 1], acc[t][4 * a + 2], acc[t][4 * a + 3]};
        *reinterpret_cast<float4*>(prow + (t * 4 + a) * 4) = f;
      }
  }
  __syncthreads();
  if (q == 1) return;

  #pragma unroll
  for (int t = 0; t < 4; ++t)
    #pragma unroll
    for (int a = 0; a < 4; ++a) {
      float4 f = *reinterpret_cast<const float4*>(prow + (t * 4 + a) * 4);
      acc[t][4 * a + 0] += f.x; acc[t][4 * a + 1] += f.y;
      acc[t][4 * a + 2] += f.z; acc[t][4 * a + 3] += f.w;
    }

  readout32(acc, mword, ws, rb_lds, lane16, l31, lh, row0 + pr * 32, out);
}

extern "C" void kernel_launch(void* const* d_in, const int* in_sizes, int n_in,
                              void* d_out, int out_size, void* d_ws, size_t ws_size,
                              hipStream_t stream) {
  const float* x    = (const float*)d_in[0];
  const int*   mask = (const int*)d_in[1];
  const float* W1   = (const float*)d_in[2];
  const float* b1   = (const float*)d_in[3];
  const float* W2   = (const float*)d_in[4];
  const float* b2   = (const float*)d_in[5];
  const float* W3   = (const float*)d_in[6];
  const float* b3   = (const float*)d_in[7];
  const float* rW1  = (const float*)d_in[8];
  const float* rb1  = (const float*)d_in[9];
  const float* rW2  = (const float*)d_in[10];
  const float* rb2  = (const float*)d_in[11];
  const float* rW3  = (const float*)d_in[12];
  const float* rb3  = (const float*)d_in[13];
  float* out = (float*)d_out;
  f16_t* ws = (f16_t*)d_ws;

  convert_weights<<<256, 256, 0, stream>>>(W1, b1, W2, b2, W3, b3, rW1, rW2, rW3, ws);
  indexnet_main<<<NROWS / 128, 512, 0, stream>>>(
      x, mask, rb1, rb2, rb3, ws, out);
}

// Round 14
// 49.836 us; speedup vs baseline: 1.4969x; 1.0089x over previous
//
#include <hip/hip_runtime.h>
#include <hip/hip_bf16.h>
#include <math.h>

typedef _Float16 f16_t;
typedef _Float16 f16x8 __attribute__((ext_vector_type(8)));
typedef float f32x16 __attribute__((ext_vector_type(16)));
typedef unsigned int uintx4 __attribute__((ext_vector_type(4)));
typedef unsigned int uintx2 __attribute__((ext_vector_type(2)));

#define NROWS 32768
#define DD 32
#define SIG_OFF (NROWS * 64)

// ---------------- ws layout (f16 elements) -- identical to round 13 ----------
// Fragment order: [tile][ks][lane][j], n = t*32+(lane&31), k = ks*16+(lane>>5)*8+j.
// Per-d superblock (K=80 GEMM1 with b2 folded as the k=64 row):
//   wf2ext: 2t x 5ks x 512 = 5120  (ks=4 fragment: (lh==0&&j==0) ? b2[d][n] : 0)
//   wf3   : 4t x 4ks x 512 = 8192
#define PERD_STRIDE 13312
#define W1B1F_OFF   425984         // 32*13312; [32 d][128]: w1|b1
#define RW1F_OFF    430080
#define RW2F_OFF    438272
#define RW3F_OFF    442368
#define B3F_OFF     450560
#define WS_ELEMS    454656

__global__ void convert_weights(const float* __restrict__ W1,
                                const float* __restrict__ b1,
                                const float* __restrict__ W2,
                                const float* __restrict__ b2,
                                const float* __restrict__ W3,
                                const float* __restrict__ b3,
                                const float* __restrict__ rW1,
                                const float* __restrict__ rW2,
                                const float* __restrict__ rW3,
                                f16_t* __restrict__ ws) {
  for (int i = blockIdx.x * blockDim.x + threadIdx.x; i < WS_ELEMS;
       i += gridDim.x * blockDim.x) {
    float v;
    if (i < W1B1F_OFF) {
      int d = i / PERD_STRIDE;
      int r = i - d * PERD_STRIDE;
      if (r < 5120) {                 // wf2ext: K=80 (ks=4 row = b2)
        int t = r / 2560, rr = r - t * 2560;
        int ks = rr >> 9, lane = (rr >> 3) & 63, j = rr & 7;
        int n = t * 32 + (lane & 31);
        if (ks < 4) {
          int k = ks * 16 + (lane >> 5) * 8 + j;
          v = W2[(d * 64 + k) * 64 + n];
        } else {
          v = ((lane >> 5) == 0 && j == 0) ? b2[d * 64 + n] : 0.f;
        }
      } else {                        // wf3: W3[d][k][n], n<128
        int r2 = r - 5120;
        int t = r2 >> 11, ks = (r2 >> 9) & 3, lane = (r2 >> 3) & 63, j = r2 & 7;
        int n = t * 32 + (lane & 31);
        int k = ks * 16 + (lane >> 5) * 8 + j;
        v = W3[(d * 64 + k) * 128 + n];
      }
    } else if (i < RW1F_OFF) {        // w1 | b1, [d][128]
      int jj = i - W1B1F_OFF;
      int d = jj >> 7, c = jj & 127;
      v = (c < 64) ? W1[d * 64 + c] : b1[d * 64 + (c - 64)];
    } else if (i < RW2F_OFF) {        // rW1 fragments, k<128
      int i2 = i - RW1F_OFF;
      int t = i2 >> 12, ks = (i2 >> 9) & 7, lane = (i2 >> 3) & 63, j = i2 & 7;
      int n = t * 32 + (lane & 31);
      int k = ks * 16 + (lane >> 5) * 8 + j;
      v = rW1[k * 64 + n];
    } else if (i < RW3F_OFF) {        // rW2 fragments, k<64
      int i2 = i - RW2F_OFF;
      int t = i2 >> 11, ks = (i2 >> 9) & 3, lane = (i2 >> 3) & 63, j = i2 & 7;
      int n = t * 32 + (lane & 31);
      int k = ks * 16 + (lane >> 5) * 8 + j;
      v = rW2[k * 64 + n];
    } else if (i < B3F_OFF) {         // rW3 fragments, output col n<128, k<64
      int i2 = i - RW3F_OFF;
      int nt = i2 >> 11, ks = (i2 >> 9) & 3, lane = (i2 >> 3) & 63, j = i2 & 7;
      int n = nt * 32 + (lane & 31);
      int k = ks * 16 + (lane >> 5) * 8 + j;
      v = rW3[k * 128 + n];
    } else {                          // b3 as B-fragment: "k" axis = d (32)
      int i2 = i - B3F_OFF;
      int t = i2 >> 10, ks = (i2 >> 9) & 1, lane = (i2 >> 3) & 63, j = i2 & 7;
      int n = t * 32 + (lane & 31);
      int dsrc = ks * 16 + (lane >> 5) * 8 + j;
      v = b3[dsrc * 128 + n];
    }
    ws[i] = (f16_t)v;
  }
}

// REGISTER-ONLY transpose (validated r13): swapped-C tile -> two B fragments
// via cvt_pkrtz + permlane32_swap (vdst.row1 <-> vsrc.row0).
__device__ __forceinline__ void xpose2r(const f32x16& c, f16x8& o0, f16x8& o1) {
  unsigned u0 = __builtin_bit_cast(unsigned, __builtin_amdgcn_cvt_pkrtz(c[0], c[1]));
  unsigned u1 = __builtin_bit_cast(unsigned, __builtin_amdgcn_cvt_pkrtz(c[2], c[3]));
  unsigned v0 = __builtin_bit_cast(unsigned, __builtin_amdgcn_cvt_pkrtz(c[4], c[5]));
  unsigned v1 = __builtin_bit_cast(unsigned, __builtin_amdgcn_cvt_pkrtz(c[6], c[7]));
  uintx2 s0 = __builtin_amdgcn_permlane32_swap(u0, v0, false, false);
  uintx2 s1 = __builtin_amdgcn_permlane32_swap(u1, v1, false, false);
  uintx4 w0 = {s0.x, s1.x, s0.y, s1.y};
  o0 = __builtin_bit_cast(f16x8, w0);
  unsigned u2 = __builtin_bit_cast(unsigned, __builtin_amdgcn_cvt_pkrtz(c[8], c[9]));
  unsigned u3 = __builtin_bit_cast(unsigned, __builtin_amdgcn_cvt_pkrtz(c[10], c[11]));
  unsigned v2 = __builtin_bit_cast(unsigned, __builtin_amdgcn_cvt_pkrtz(c[12], c[13]));
  unsigned v3 = __builtin_bit_cast(unsigned, __builtin_amdgcn_cvt_pkrtz(c[14], c[15]));
  uintx2 s2 = __builtin_amdgcn_permlane32_swap(u2, v2, false, false);
  uintx2 s3 = __builtin_amdgcn_permlane32_swap(u3, v3, false, false);
  uintx4 w1 = {s2.x, s3.x, s2.y, s3.y};
  o1 = __builtin_bit_cast(f16x8, w1);
}

// One d-iteration (identical to r13): h1 -> GEMM1 (swapped, K=80, b2 folded)
// -> relu/mask -> register xpose -> GEMM2 (swapped, accumulate).
__device__ __forceinline__ void compute_d(const f16_t* __restrict__ wb,
                                          const f16_t* __restrict__ w1b1row,
                                          float xv, bool mb,
                                          int lane16, int lh, f32x16* acc) {
  f16x8 wf2[2][5], wf3[4][4];
  #pragma unroll
  for (int t = 0; t < 2; ++t)
    #pragma unroll
    for (int ks = 0; ks < 5; ++ks)
      wf2[t][ks] = *reinterpret_cast<const f16x8*>(wb + (t * 5 + ks) * 512 + lane16);
  #pragma unroll
  for (int t = 0; t < 4; ++t)
    #pragma unroll
    for (int ks = 0; ks < 4; ++ks)
      wf3[t][ks] = *reinterpret_cast<const f16x8*>(wb + 5120 + (t * 4 + ks) * 512 + lane16);

  f16_t xh = (f16_t)xv;
  f16x8 xv8 = {xh, xh, xh, xh, xh, xh, xh, xh};
  f16x8 h1f[5];
  #pragma unroll
  for (int ks = 0; ks < 4; ++ks) {
    f16x8 w1 = *reinterpret_cast<const f16x8*>(w1b1row + ks * 16 + lh * 8);
    f16x8 bb = *reinterpret_cast<const f16x8*>(w1b1row + 64 + ks * 16 + lh * 8);
    f16x8 h = xv8 * w1 + bb;
    h1f[ks] = __builtin_elementwise_max(h, (f16x8)(f16_t)0);
  }
  h1f[4] = (f16x8)(f16_t)0;
  h1f[4][0] = (lh == 0) ? (f16_t)1.0f : (f16_t)0.0f;  // h1_ext[k=64] = 1

  f32x16 hacc[2] = {};   // b2 arrives via the ks=4 MFMA
  #pragma unroll
  for (int ks = 0; ks < 5; ++ks) {
    hacc[0] = __builtin_amdgcn_mfma_f32_32x32x16_f16(wf2[0][ks], h1f[ks], hacc[0], 0, 0, 0);
    hacc[1] = __builtin_amdgcn_mfma_f32_32x32x16_f16(wf2[1][ks], h1f[ks], hacc[1], 0, 0, 0);
  }
  #pragma unroll
  for (int t = 0; t < 2; ++t)
    #pragma unroll
    for (int r = 0; r < 16; ++r) {
      float v = fmaxf(hacc[t][r], 0.f);
      hacc[t][r] = mb ? v : 0.f;
    }
  f16x8 pf[4];
  xpose2r(hacc[0], pf[0], pf[1]);
  xpose2r(hacc[1], pf[2], pf[3]);
  #pragma unroll
  for (int t = 0; t < 4; ++t)
    #pragma unroll
    for (int ks = 0; ks < 4; ++ks)
      acc[t] = __builtin_amdgcn_mfma_f32_32x32x16_f16(wf3[t][ks], pf[ks], acc[t], 0, 0, 0);
}

// Stage one full 26.6KB d-superblock of stream q: its 2 pr-waves each DMA
// 13.3KB global->LDS (13 x 1KB rounds; no VGPR round-trip). The following
// __syncthreads drains vmcnt (r12/r13-validated pattern).
__device__ __forceinline__ void stage_sb(const f16_t* __restrict__ ws,
                                         f16_t* __restrict__ dstbase,
                                         int pr, int lane, int d) {
  const f16_t* src = ws + (size_t)d * PERD_STRIDE + pr * 6656 + lane * 8;
  f16_t* dst = dstbase + pr * 6656;
  #pragma unroll
  for (int c = 0; c < 13; ++c)
    __builtin_amdgcn_global_load_lds(
        (const __attribute__((address_space(1))) void*)(src + c * 512),
        (__attribute__((address_space(3))) void*)(dst + c * 512), 16, 0, 0);
}

// Readout chain for one 32-row subtile (identical to r13).
__device__ __forceinline__ void readout32(f32x16* acc, unsigned mword,
                                          const f16_t* __restrict__ ws,
                                          const float* __restrict__ rb,
                                          int lane16, int l31, int lh,
                                          int rowb, float* __restrict__ out) {
  {
    f16x8 mf[2];
    #pragma unroll
    for (int ks = 0; ks < 2; ++ks) {
      unsigned w[4];
      #pragma unroll
      for (int ii = 0; ii < 4; ++ii) {
        int d0 = ks * 16 + lh * 8 + 2 * ii;
        w[ii] = (((mword >> d0) & 1u) ? 0x3C00u : 0u) |
                (((mword >> (d0 + 1)) & 1u) ? 0x3C000000u : 0u);
      }
      uintx4 ww = {w[0], w[1], w[2], w[3]};
      mf[ks] = __builtin_bit_cast(f16x8, ww);
    }
    const f16_t* b3f = ws + B3F_OFF;
    #pragma unroll
    for (int t = 0; t < 4; ++t)
      #pragma unroll
      for (int ks = 0; ks < 2; ++ks) {
        f16x8 bf = *reinterpret_cast<const f16x8*>(b3f + (t * 2 + ks) * 512 + lane16);
        acc[t] = __builtin_amdgcn_mfma_f32_32x32x16_f16(bf, mf[ks], acc[t], 0, 0, 0);
      }
  }
  f16x8 poolf[8];
  xpose2r(acc[0], poolf[0], poolf[1]);
  xpose2r(acc[1], poolf[2], poolf[3]);
  xpose2r(acc[2], poolf[4], poolf[5]);
  xpose2r(acc[3], poolf[6], poolf[7]);
  f32x16 r1[2];
  #pragma unroll
  for (int t = 0; t < 2; ++t)
    #pragma unroll
    for (int a = 0; a < 4; ++a) {
      float4 bv = *reinterpret_cast<const float4*>(&rb[t * 32 + a * 8 + lh * 4]);
      r1[t][4 * a + 0] = bv.x; r1[t][4 * a + 1] = bv.y;
      r1[t][4 * a + 2] = bv.z; r1[t][4 * a + 3] = bv.w;
    }
  {
    const f16_t* rw1 = ws + RW1F_OFF;
    #pragma unroll
    for (int t = 0; t < 2; ++t)
      #pragma unroll
      for (int ks = 0; ks < 8; ++ks) {
        f16x8 wf = *reinterpret_cast<const f16x8*>(rw1 + (t * 8 + ks) * 512 + lane16);
        r1[t] = __builtin_amdgcn_mfma_f32_32x32x16_f16(wf, poolf[ks], r1[t], 0, 0, 0);
      }
  }
  #pragma unroll
  for (int t = 0; t < 2; ++t)
    #pragma unroll
    for (int r = 0; r < 16; ++r) r1[t][r] = fmaxf(r1[t][r], 0.f);

  f16x8 r1f[4];
  xpose2r(r1[0], r1f[0], r1f[1]);
  xpose2r(r1[1], r1f[2], r1f[3]);
  f32x16 r2[2];
  #pragma unroll
  for (int t = 0; t < 2; ++t)
    #pragma unroll
    for (int a = 0; a < 4; ++a) {
      float4 bv = *reinterpret_cast<const float4*>(&rb[64 + t * 32 + a * 8 + lh * 4]);
      r2[t][4 * a + 0] = bv.x; r2[t][4 * a + 1] = bv.y;
      r2[t][4 * a + 2] = bv.z; r2[t][4 * a + 3] = bv.w;
    }
  {
    const f16_t* rw2 = ws + RW2F_OFF;
    #pragma unroll
    for (int t = 0; t < 2; ++t)
      #pragma unroll
      for (int ks = 0; ks < 4; ++ks) {
        f16x8 wf = *reinterpret_cast<const f16x8*>(rw2 + (t * 4 + ks) * 512 + lane16);
        r2[t] = __builtin_amdgcn_mfma_f32_32x32x16_f16(wf, r1f[ks], r2[t], 0, 0, 0);
      }
  }
  #pragma unroll
  for (int t = 0; t < 2; ++t)
    #pragma unroll
    for (int r = 0; r < 16; ++r) r2[t][r] = fmaxf(r2[t][r], 0.f);

  f16x8 r2f[4];
  xpose2r(r2[0], r2f[0], r2f[1]);
  xpose2r(r2[1], r2f[2], r2f[3]);
  f32x16 oacc[4] = {};
  {
    const f16_t* rw3 = ws + RW3F_OFF;
    #pragma unroll
    for (int nt = 0; nt < 4; ++nt)
      #pragma unroll
      for (int ks = 0; ks < 4; ++ks) {
        f16x8 wf = *reinterpret_cast<const f16x8*>(rw3 + (nt * 4 + ks) * 512 + lane16);
        oacc[nt] = __builtin_amdgcn_mfma_f32_32x32x16_f16(r2f[ks], wf, oacc[nt], 0, 0, 0);
      }
  }
  #pragma unroll
  for (int nt = 0; nt < 4; ++nt) {
    float rbv = rb[128 + nt * 32 + l31];
    #pragma unroll
    for (int r = 0; r < 16; ++r) {
      int rl = (r & 3) + 8 * (r >> 2) + 4 * lh;
      size_t grow = (size_t)(rowb + rl);
      float v = oacc[nt][r] + rbv;
      if (nt < 2) {
        out[grow * 64 + nt * 32 + l31] = v;
      } else {
        float sp = fmaxf(v, 0.f) + __logf(1.f + __expf(-fabsf(v)));
        out[(size_t)SIG_OFF + grow * 64 + (nt - 2) * 32 + l31] = sp;
      }
    }
  }
}

// Round 14 = round 13 compute, reshaped for CROSS-BLOCK OVERLAP.
// Block = 256 thr = 4 waves = 2 pr (32-row groups) x 2 q (d-halves).
// Grid = 512 = 2 blocks/CU (LDS 62.5KB <= 80KB). r13's post-mortem: at
// 7000 cyc/iter wall vs ~500 cyc issue, all 8 waves of the CU sat in ONE
// block's barrier+DMA-drain lockstep. Now, while block A drains its
// single-buffered refill window (compute -> barrier -> DMA -> barrier),
// block B computes -- the convoy stall is hidden by an independent block,
// with no new sync semantics (r12/r13-proven patterns only).
__launch_bounds__(256, 2)
__global__ void indexnet_main(const float* __restrict__ x,
                              const int* __restrict__ mask,
                              const float* __restrict__ rb1,
                              const float* __restrict__ rb2,
                              const float* __restrict__ rb3,
                              const f16_t* __restrict__ ws,
                              float* __restrict__ out) {
  __shared__ __align__(16) f16_t wbuf[2][13312];       // 2 streams x 26.6KB
  __shared__ __align__(16) f16_t w1b1_lds[32][128];    // 8KB
  __shared__ float rb_lds[256];                        // 1KB
  // total 62.5KB -> 2 blocks/CU

  const int tid = threadIdx.x;
  const int lane = tid & 63;
  const int wid = tid >> 6;
  const int pr = wid >> 1;         // row group (0..1)
  const int q = wid & 1;           // d-half / stream
  const int l31 = lane & 31;
  const int lh = lane >> 5;
  const int row0 = blockIdx.x * 64;
  const int lane16 = lane * 8;

  // ---- stage readout biases ----
  if (tid < 64)        rb_lds[tid] = rb1[tid];
  else if (tid < 128)  rb_lds[tid] = rb2[tid - 64];
  else                 rb_lds[tid] = rb3[tid - 128];
  // ---- stage w1|b1 [32][128] f16 (256 thr x 2 x 16B) ----
  {
    const uintx4* src = reinterpret_cast<const uintx4*>(ws + W1B1F_OFF);
    uintx4* dst = reinterpret_cast<uintx4*>(&w1b1_lds[0][0]);
    dst[tid * 2] = src[tid * 2];
    dst[tid * 2 + 1] = src[tid * 2 + 1];
  }
  // ---- per-lane mask word for own row ----
  unsigned mword = 0;
  {
    const int4* mrow = reinterpret_cast<const int4*>(mask + (size_t)(row0 + pr * 32 + l31) * DD);
    #pragma unroll
    for (int c4 = 0; c4 < 8; ++c4) {
      int4 m = mrow[c4];
      mword |= (m.x != 0 ? 1u : 0u) << (4 * c4);
      mword |= (m.y != 0 ? 1u : 0u) << (4 * c4 + 1);
      mword |= (m.z != 0 ? 1u : 0u) << (4 * c4 + 2);
      mword |= (m.w != 0 ? 1u : 0u) << (4 * c4 + 3);
    }
  }
  const float* xrow = x + (size_t)(row0 + pr * 32 + l31) * DD + q * 16;
  const int dbase = q * 16;

  // ---- prologue: DMA each stream's first superblock ----
  stage_sb(ws, &wbuf[q][0], pr, lane, dbase);
  __syncthreads();   // drains DMA; biases/w1b1 ready

  f32x16 acc[4] = {};   // pooled^T: tile t -> n = 32t + rl, lane = row

  for (int dd0 = 0; dd0 < 16; dd0 += 4) {
    float4 xv4 = *reinterpret_cast<const float4*>(xrow + dd0);
    #pragma unroll
    for (int j = 0; j < 4; ++j) {
      const int i = dd0 + j;
      const int d = dbase + i;
      float xv = (j == 0) ? xv4.x : (j == 1) ? xv4.y : (j == 2) ? xv4.z : xv4.w;
      compute_d(&wbuf[q][0], &w1b1_lds[d][0], xv,
                (mword >> d) & 1u, lane16, lh, acc);
      if (i < 15) {
        __syncthreads();   // all reads of wbuf[q] complete
        stage_sb(ws, &wbuf[q][0], pr, lane, dbase + i + 1);
        __syncthreads();   // drains DMA -> next superblock visible
      }
    }
  }
  __syncthreads();   // last compute done before pool aliases wbuf

  // ---- pool combine across q-halves (pool area aliases dead wbuf) ----
  float* pool_ex = reinterpret_cast<float*>(&wbuf[0][0]);
  float* prow = pool_ex + (((size_t)pr * 2 + lh) * 32 + l31) * 68;
  if (q == 1) {
    #pragma unroll
    for (int t = 0; t < 4; ++t)
      #pragma unroll
      for (int a = 0; a < 4; ++a) {
        float4 f = {acc[t][4 * a], acc[t][4 * a + 1], acc[t][4 * a + 2], acc[t][4 * a + 3]};
        *reinterpret_cast<float4*>(prow + (t * 4 + a) * 4) = f;
      }
  }
  __syncthreads();
  if (q == 1) return;

  #pragma unroll
  for (int t = 0; t < 4; ++t)
    #pragma unroll
    for (int a = 0; a < 4; ++a) {
      float4 f = *reinterpret_cast<const float4*>(prow + (t * 4 + a) * 4);
      acc[t][4 * a + 0] += f.x; acc[t][4 * a + 1] += f.y;
      acc[t][4 * a + 2] += f.z; acc[t][4 * a + 3] += f.w;
    }

  readout32(acc, mword, ws, rb_lds, lane16, l31, lh, row0 + pr * 32, out);
}

extern "C" void kernel_launch(void* const* d_in, const int* in_sizes, int n_in,
                              void* d_out, int out_size, void* d_ws, size_t ws_size,
                              hipStream_t stream) {
  const float* x    = (const float*)d_in[0];
  const int*   mask = (const int*)d_in[1];
  const float* W1   = (const float*)d_in[2];
  const float* b1   = (const float*)d_in[3];
  const float* W2   = (const float*)d_in[4];
  const float* b2   = (const float*)d_in[5];
  const float* W3   = (const float*)d_in[6];
  const float* b3   = (const float*)d_in[7];
  const float* rW1  = (const float*)d_in[8];
  const float* rb1  = (const float*)d_in[9];
  const float* rW2  = (const float*)d_in[10];
  const float* rb2  = (const float*)d_in[11];
  const float* rW3  = (const float*)d_in[12];
  const float* rb3  = (const float*)d_in[13];
  float* out = (float*)d_out;
  f16_t* ws = (f16_t*)d_ws;

  convert_weights<<<256, 256, 0, stream>>>(W1, b1, W2, b2, W3, b3, rW1, rW2, rW3, ws);
  indexnet_main<<<NROWS / 64, 256, 0, stream>>>(
      x, mask, rb1, rb2, rb3, ws, out);
}